// Round 9
// baseline (607.786 us; speedup 1.0000x reference)
//
#include <hip/hip_runtime.h>
#include <math.h>

#define N_NODES 100000
#define N_EDGES 3200000
#define F_IN    512
#define HIDDEN  256
#define NCLASS  40
#define NPAD    48
#define H2STRIDE 64
#define FB_ROWS 16
#define G1_BLOCKS ((N_NODES + 63) / 64)          // 1563
#define FILL_BLOCKS (N_EDGES / 256)              // 12500

#define SCAN_B  256
#define N_SCANB ((N_NODES + SCAN_B - 1) / SCAN_B)   // 391

typedef __attribute__((ext_vector_type(8))) _Float16 half8;
typedef __attribute__((ext_vector_type(4))) _Float16 half4;
typedef __attribute__((ext_vector_type(4))) float    f32x4;

// ---------------------------------------------------------------------------
// hist2: histogram + per-edge rank; blocks 0..511 also convert W1 -> W1T;
// block 512 zeroes the scan's publish array.
// ---------------------------------------------------------------------------
__global__ __launch_bounds__(256) void hist2_kernel(const int* __restrict__ erow,
                                                    int* __restrict__ deg,
                                                    unsigned short* __restrict__ ke, int E,
                                                    const float* __restrict__ W1,
                                                    _Float16* __restrict__ W1T,
                                                    int* __restrict__ pub) {
    int b = blockIdx.x, t = threadIdx.x;
    int e = b * 256 + t;
    if (e < E) ke[e] = (unsigned short)atomicAdd(&deg[erow[e]], 1);
    if (b < 512) {
        int o = b * 256 + t;                 // 0..131071
        int n = o >> 9, k = o & 511;
        W1T[o] = (_Float16)W1[(size_t)k * HIDDEN + n];
    }
    if (b == 512) {
        for (int j = t; j < N_SCANB + 1; j += 256) pub[j] = 0;
    }
}

// ---------------------------------------------------------------------------
// Single-dispatch exclusive scan (decoupled lookback, 391 blocks).
// Publishes aggregate+1 (0 = not ready). Block 0 also converts W2 -> W2T.
// Deterministic: integer sums, order-independent lookback.
// ---------------------------------------------------------------------------
__global__ __launch_bounds__(256) void scan_fused_kernel(const int* __restrict__ deg,
                                                         int* __restrict__ rptr,
                                                         int* __restrict__ pub,
                                                         const float* __restrict__ W2,
                                                         _Float16* __restrict__ W2T,
                                                         int n, int E) {
    __shared__ int s[SCAN_B];
    __shared__ int wsum[4];
    int b = blockIdx.x, t = threadIdx.x;

    // block 0 extra: W2 [256][40] f32 -> W2T [48][256] fp16 (padded cols zeroed)
    if (b == 0) {
        for (int o = t; o < NPAD * HIDDEN; o += 256) {
            int nn = o >> 8, k = o & 255;
            W2T[o] = (nn < NCLASS) ? (_Float16)W2[(size_t)k * NCLASS + nn] : (_Float16)0.f;
        }
    }

    int i = b * SCAN_B + t;
    int v = (i < n) ? deg[i] : 0;
    s[t] = v;
    __syncthreads();
    #pragma unroll
    for (int off = 1; off < SCAN_B; off <<= 1) {
        int x = (t >= off) ? s[t - off] : 0;
        __syncthreads();
        s[t] += x;
        __syncthreads();
    }

    // publish this block's aggregate (+1 so 0 == not-ready)
    if (t == 0) atomicExch(&pub[b], s[SCAN_B - 1] + 1);

    // lookback: sum aggregates of blocks 0..b-1 (spin until published)
    int part = 0;
    for (int j = t; j < b; j += 256) {
        int pv;
        do { pv = atomicAdd(&pub[j], 0); } while (pv == 0);
        part += pv - 1;
    }
    #pragma unroll
    for (int off = 32; off >= 1; off >>= 1) part += __shfl_xor(part, off);
    if ((t & 63) == 0) wsum[t >> 6] = part;
    __syncthreads();
    int offset = wsum[0] + wsum[1] + wsum[2] + wsum[3];

    if (i < n) rptr[i] = offset + s[t] - v;      // exclusive prefix
    if (b == 0 && t == 0) rptr[n] = E;
}

// ---------------------------------------------------------------------------
// MERGED: blocks [0, G1_BLOCKS) = GEMM1 ; blocks [G1_BLOCKS, +FILL_BLOCKS) = fill
// ---------------------------------------------------------------------------
__global__ __launch_bounds__(256) void fill_gemm1_kernel(
        const float* __restrict__ A, const _Float16* __restrict__ BT,
        _Float16* __restrict__ C, int M,
        const int* __restrict__ erow, const int* __restrict__ ecol,
        const float* __restrict__ evals, const int* __restrict__ rptr,
        const unsigned short* __restrict__ ke, int2* __restrict__ cv, int E) {
    __shared__ __align__(16) char smem[33792];

    if (blockIdx.x >= G1_BLOCKS) {
        // ---- fill: permute (col,val) -> CSR slots, no atomics ----
        int e = (blockIdx.x - G1_BLOCKS) * 256 + threadIdx.x;
        if (e < E) {
            int p = rptr[erow[e]] + ke[e];
            cv[p] = make_int2(ecol[e], __float_as_int(evals[e]));
        }
        return;
    }

    // ---- GEMM1 (MFMA fp16): tile 64(M) x 256(N), x read once ----
    _Float16 (*As)[40]  = (_Float16 (*)[40])smem;              //  64x40  = 5120 B
    _Float16 (*Bs)[40]  = (_Float16 (*)[40])(smem + 5120);     // 256x40  = 20480 B
    _Float16 (*sC)[264] = (_Float16 (*)[264])smem;             //  64x264 = 33792 B

    const int t    = threadIdx.x;
    const int m0   = blockIdx.x * 64;
    const int lane = t & 63;
    const int wid  = t >> 6;
    const int lr   = lane & 15, lk = lane >> 4;

    f32x4 acc[4][4] = {};

    const int  ar   = t >> 2;            // 0..63
    const int  aq   = t & 3;             // 0..3
    const bool aval = (m0 + ar) < M;
    const float*    aptr = A  + (size_t)(m0 + ar) * F_IN + aq * 8;
    const _Float16* bptr = BT + (size_t)t * F_IN;              // row t of BT

    float4 a0 = {0.f,0.f,0.f,0.f}, a1 = {0.f,0.f,0.f,0.f};
    half8 b0, b1, b2, b3;
    if (aval) { a0 = *(const float4*)(aptr); a1 = *(const float4*)(aptr + 4); }
    { const half8* bp = (const half8*)(bptr); b0 = bp[0]; b1 = bp[1]; b2 = bp[2]; b3 = bp[3]; }

    for (int k0 = 0; k0 < F_IN; k0 += 32) {
        half8 ah;
        ah[0]=(_Float16)a0.x; ah[1]=(_Float16)a0.y; ah[2]=(_Float16)a0.z; ah[3]=(_Float16)a0.w;
        ah[4]=(_Float16)a1.x; ah[5]=(_Float16)a1.y; ah[6]=(_Float16)a1.z; ah[7]=(_Float16)a1.w;
        *(half8*)&As[ar][aq * 8] = ah;
        *(half8*)&Bs[t][0]  = b0;
        *(half8*)&Bs[t][8]  = b1;
        *(half8*)&Bs[t][16] = b2;
        *(half8*)&Bs[t][24] = b3;
        __syncthreads();

        if (k0 + 32 < F_IN) {
            if (aval) {
                a0 = *(const float4*)(aptr + k0 + 32);
                a1 = *(const float4*)(aptr + k0 + 36);
            }
            const half8* bp = (const half8*)(bptr + k0 + 32);
            b0 = bp[0]; b1 = bp[1]; b2 = bp[2]; b3 = bp[3];
        }

        half8 af[4], bf[4];
        #pragma unroll
        for (int fm = 0; fm < 4; fm++) af[fm] = *(half8*)&As[fm * 16 + lr][lk * 8];
        #pragma unroll
        for (int fn = 0; fn < 4; fn++) bf[fn] = *(half8*)&Bs[wid * 64 + fn * 16 + lr][lk * 8];
        #pragma unroll
        for (int fm = 0; fm < 4; fm++)
            #pragma unroll
            for (int fn = 0; fn < 4; fn++)
                acc[fm][fn] = __builtin_amdgcn_mfma_f32_16x16x32_f16(af[fm], bf[fn], acc[fm][fn], 0, 0, 0);
        __syncthreads();
    }

    #pragma unroll
    for (int fm = 0; fm < 4; fm++)
        #pragma unroll
        for (int fn = 0; fn < 4; fn++)
            #pragma unroll
            for (int j = 0; j < 4; j++) {
                int row = fm * 16 + lk * 4 + j;
                int col = wid * 64 + fn * 16 + lr;
                sC[row][col] = (_Float16)acc[fm][fn][j];
            }
    __syncthreads();

    int m = m0 + ar;
    if (m < M) {
        const float4* sp = (const float4*)&sC[ar][aq * 64];
        float4*       dp = (float4*)(C + (size_t)m * HIDDEN + aq * 64);
        #pragma unroll
        for (int j = 0; j < 8; j++) dp[j] = sp[j];
    }
}

// ---------------------------------------------------------------------------
// FUSED: SpMM gather D=256 (fp16) + ReLU + GEMM2 (@W2 via MFMA epilogue).
// 1024 threads = 16 waves = 16 rows; rows staged in LDS; one barrier;
// wave 0 computes H2[16 rows][48] with 24 MFMAs.
// ---------------------------------------------------------------------------
__global__ __launch_bounds__(1024) void spmm_gemm2_kernel(const int* __restrict__ rptr,
                                                          const int2* __restrict__ cv,
                                                          const _Float16* __restrict__ H1,
                                                          const _Float16* __restrict__ W2T,
                                                          _Float16* __restrict__ H2) {
    __shared__ _Float16 sW2[NPAD][264];     // 25344 B
    __shared__ _Float16 sRow[16][264];      //  8448 B

    int t = threadIdx.x;
    int wave = t >> 6, lane = t & 63;
    int m0 = blockIdx.x * FB_ROWS;
    int r = m0 + wave;

    // stage W2T (48x256 = 1536 half8 chunks) : 1.5 per thread
    #pragma unroll
    for (int i = 0; i < 2; i++) {
        int idx = t + i * 1024;             // 0..2047
        if (idx < NPAD * 32) {
            int row = idx >> 5, c8 = idx & 31;
            *(half8*)&sW2[row][c8 * 8] = *(const half8*)(W2T + (size_t)row * HIDDEN + c8 * 8);
        }
    }

    // gather: 2 edges per instr (32 lanes x 16B cover one 512B row), 8 edges/iter
    int e0 = rptr[r], e1 = rptr[r + 1];
    int hf = lane >> 5;
    int fl = lane & 31;

    float acc[8] = {};
    for (int e = e0; e < e1; e += 8) {
        #pragma unroll
        for (int u = 0; u < 4; u++) {
            int idx = e + 2 * u + hf;
            bool ok = idx < e1;
            int2 p = cv[ok ? idx : e0];
            float v = ok ? __int_as_float(p.y) : 0.f;
            half8 h = *(const half8*)(H1 + (size_t)p.x * HIDDEN + fl * 8);
            #pragma unroll
            for (int j = 0; j < 8; j++)
                acc[j] += v * (float)h[j];
        }
    }
    #pragma unroll
    for (int j = 0; j < 8; j++)
        acc[j] += __shfl_xor(acc[j], 32);

    if (hf == 0) {
        half8 o;
        #pragma unroll
        for (int j = 0; j < 8; j++) o[j] = (_Float16)fmaxf(acc[j], 0.f);
        *(half8*)&sRow[wave][fl * 8] = o;
    }
    __syncthreads();

    // MFMA epilogue on wave 0: [16x256] @ [48x256]^T
    if (wave == 0) {
        int lr = lane & 15, lk = lane >> 4;
        f32x4 acc2[3] = {};
        #pragma unroll
        for (int ks = 0; ks < 8; ks++) {
            half8 af = *(half8*)&sRow[lr][ks * 32 + lk * 8];
            #pragma unroll
            for (int fn = 0; fn < 3; fn++) {
                half8 bf = *(half8*)&sW2[fn * 16 + lr][ks * 32 + lk * 8];
                acc2[fn] = __builtin_amdgcn_mfma_f32_16x16x32_f16(af, bf, acc2[fn], 0, 0, 0);
            }
        }
        #pragma unroll
        for (int fn = 0; fn < 3; fn++)
            #pragma unroll
            for (int j = 0; j < 4; j++) {
                int row = lk * 4 + j;       // 0..15
                int col = fn * 16 + lr;     // 0..47
                H2[(size_t)(m0 + row) * H2STRIDE + col] = (_Float16)acc2[fn][j];
            }
    }
}

// ---------------------------------------------------------------------------
// SpMM gather D=40 (fp16, stride-64 rows = one 128B line/edge) + ReLU +
// log_softmax. One wave per row; 24 edges/iter.
// ---------------------------------------------------------------------------
__global__ __launch_bounds__(256) void spmm40_ls_kernel(const int* __restrict__ rptr,
                                                        const int2* __restrict__ cv,
                                                        const _Float16* __restrict__ H2,
                                                        float* __restrict__ out) {
    int t = threadIdx.x;
    int wave = t >> 6, lane = t & 63;
    int r = blockIdx.x * 4 + wave;

    int e0 = rptr[r], e1 = rptr[r + 1];
    int s = lane / 5;           // edge slot 0..11 (lane 60..63 inactive)
    int g = lane % 5;           // feature block: classes g*8 .. g*8+7
    bool lact = lane < 60;

    float acc[8] = {};
    for (int e = e0; e < e1; e += 24) {
        int idx0 = e + s, idx1 = e + 12 + s;
        bool ok0 = lact && (idx0 < e1);
        bool ok1 = lact && (idx1 < e1);
        int2 p0 = cv[ok0 ? idx0 : e0];
        int2 p1 = cv[ok1 ? idx1 : e0];
        float v0 = ok0 ? __int_as_float(p0.y) : 0.f;
        float v1 = ok1 ? __int_as_float(p1.y) : 0.f;
        half8 h0 = *(const half8*)(H2 + (size_t)p0.x * H2STRIDE + g * 8);
        half8 h1 = *(const half8*)(H2 + (size_t)p1.x * H2STRIDE + g * 8);
        #pragma unroll
        for (int j = 0; j < 8; j++)
            acc[j] += v0 * (float)h0[j] + v1 * (float)h1[j];
    }

    // slot-tree reduce: 12 -> 6 -> 3 -> 1
    #pragma unroll
    for (int j = 0; j < 8; j++) acc[j] += __shfl(acc[j], lane + 30);
    #pragma unroll
    for (int j = 0; j < 8; j++) acc[j] += __shfl(acc[j], lane + 15);
    #pragma unroll
    for (int j = 0; j < 8; j++) {
        float t1 = __shfl(acc[j], lane + 5);
        float t2 = __shfl(acc[j], lane + 10);
        acc[j] += t1 + t2;
    }

    bool act = lane < 5;
    float z[8];
    float mx = -INFINITY;
    #pragma unroll
    for (int j = 0; j < 8; j++) {
        z[j] = act ? fmaxf(acc[j], 0.f) : -INFINITY;
        mx = fmaxf(mx, z[j]);
    }
    mx = fmaxf(mx, __shfl_xor(mx, 1));
    mx = fmaxf(mx, __shfl_xor(mx, 2));
    mx = fmaxf(mx, __shfl_xor(mx, 4));

    float sm = 0.f;
    #pragma unroll
    for (int j = 0; j < 8; j++)
        sm += act ? expf(z[j] - mx) : 0.f;
    sm += __shfl_xor(sm, 1);
    sm += __shfl_xor(sm, 2);
    sm += __shfl_xor(sm, 4);

    float lse = logf(sm);
    if (act) {
        float4 o0 = {z[0]-mx-lse, z[1]-mx-lse, z[2]-mx-lse, z[3]-mx-lse};
        float4 o1 = {z[4]-mx-lse, z[5]-mx-lse, z[6]-mx-lse, z[7]-mx-lse};
        float4* dp = (float4*)(out + (size_t)r * NCLASS + g * 8);
        dp[0] = o0;
        dp[1] = o1;
    }
}

// ---------------------------------------------------------------------------
extern "C" void kernel_launch(void* const* d_in, const int* in_sizes, int n_in,
                              void* d_out, int out_size, void* d_ws, size_t ws_size,
                              hipStream_t stream) {
    const float* x     = (const float*)d_in[0];
    const int*   erow  = (const int*)d_in[1];
    const int*   ecol  = (const int*)d_in[2];
    const float* evals = (const float*)d_in[3];
    const float* W1    = (const float*)d_in[4];
    const float* W2    = (const float*)d_in[5];
    float* out = (float*)d_out;

    const int M = N_NODES;
    const int E = N_EDGES;

    char* p = (char*)d_ws;
    auto alloc = [&](size_t bytes) {
        char* q = p;
        p += (bytes + 255) & ~(size_t)255;
        return q;
    };
    int*            deg  = (int*)alloc(sizeof(int) * N_NODES);
    int*            rptr = (int*)alloc(sizeof(int) * (N_NODES + 1));
    int*            pub  = (int*)alloc(sizeof(int) * 512);
    unsigned short* ke   = (unsigned short*)alloc(sizeof(unsigned short) * N_EDGES); // 6.4 MB
    int2*           cv   = (int2*)alloc(sizeof(int2) * N_EDGES);                     // 25.6 MB
    _Float16*       W1T  = (_Float16*)alloc(sizeof(_Float16) * F_IN * HIDDEN);
    _Float16*       W2T  = (_Float16*)alloc(sizeof(_Float16) * NPAD * HIDDEN);
    _Float16*       H1   = (_Float16*)alloc(sizeof(_Float16) * (size_t)N_NODES * HIDDEN);   // 51.2 MB
    _Float16*       H2   = (_Float16*)alloc(sizeof(_Float16) * (size_t)N_NODES * H2STRIDE); // 12.8 MB

    // K1: deg = 0
    hipMemsetAsync(deg, 0, sizeof(int) * N_NODES, stream);

    // K2: histogram + per-edge rank  (+ W1->W1T in blocks 0..511, pub zero in block 512)
    hist2_kernel<<<E / 256, 256, 0, stream>>>(erow, deg, ke, E, W1, W1T, pub);

    // K3: single-dispatch exclusive scan (+ W2->W2T in block 0)
    scan_fused_kernel<<<N_SCANB, SCAN_B, 0, stream>>>(deg, rptr, pub, W2, W2T, N_NODES, E);

    // K4: merged GEMM1 (blocks 0..1562)  ||  CSR fill (blocks 1563..14062)
    fill_gemm1_kernel<<<G1_BLOCKS + FILL_BLOCKS, 256, 0, stream>>>(
        x, W1T, H1, M, erow, ecol, evals, rptr, ke, cv, E);

    // K5: fused layer-1 aggregation + relu + @W2 (MFMA epilogue), 16 rows/block
    spmm_gemm2_kernel<<<M / FB_ROWS, 1024, 0, stream>>>(rptr, cv, H1, W2T, H2);

    // K6: layer-2 aggregation + relu + log_softmax
    spmm40_ls_kernel<<<M / 4, 256, 0, stream>>>(rptr, cv, H2, out);
}

// Round 10
// 586.208 us; speedup vs baseline: 1.0368x; 1.0368x over previous
//
#include <hip/hip_runtime.h>
#include <math.h>

#define N_NODES 100000
#define N_EDGES 3200000
#define F_IN    512
#define HIDDEN  256
#define NCLASS  40
#define NPAD    48
#define H2STRIDE 64
#define FB_ROWS 16
#define G1_BLOCKS ((N_NODES + 63) / 64)          // 1563
#define FILL_BLOCKS (N_EDGES / 256)              // 12500

#define SCAN_B  256
#define N_SCANB ((N_NODES + SCAN_B - 1) / SCAN_B)   // 391

typedef __attribute__((ext_vector_type(8))) _Float16 half8;
typedef __attribute__((ext_vector_type(4))) _Float16 half4;
typedef __attribute__((ext_vector_type(4))) float    f32x4;

__device__ __forceinline__ float unpack_val(unsigned pk) {
    unsigned short hb = (unsigned short)(pk & 0x7FFFu);
    _Float16 h = *(_Float16*)&hb;
    return (float)h;
}

// ---------------------------------------------------------------------------
// init: deg = 0  +  W1 -> W1T [256][512] fp16  +  W2 -> W2T [48][256] fp16
// ---------------------------------------------------------------------------
__global__ __launch_bounds__(256) void init_kernel(const float* __restrict__ W1,
                                                   const float* __restrict__ W2,
                                                   _Float16* __restrict__ W1T,
                                                   _Float16* __restrict__ W2T,
                                                   int* __restrict__ deg) {
    int o = blockIdx.x * 256 + threadIdx.x;   // 0..131071
    {
        int n = o >> 9, k = o & 511;
        W1T[o] = (_Float16)W1[(size_t)k * HIDDEN + n];
    }
    if (o < NPAD * HIDDEN) {                  // 0..12287
        int n = o >> 8, k = o & 255;
        W2T[o] = (n < NCLASS) ? (_Float16)W2[(size_t)k * NCLASS + n] : (_Float16)0.f;
    }
    if (o < N_NODES) deg[o] = 0;
}

// ---------------------------------------------------------------------------
// CSR build: pass 1 = histogram + per-edge rank (atomic return value)
// ---------------------------------------------------------------------------
__global__ __launch_bounds__(256) void hist2_kernel(const int* __restrict__ erow,
                                                    int* __restrict__ deg,
                                                    unsigned short* __restrict__ ke, int E) {
    int e = blockIdx.x * 256 + threadIdx.x;
    if (e < E) ke[e] = (unsigned short)atomicAdd(&deg[erow[e]], 1);
}

__global__ __launch_bounds__(256) void scanA_kernel(const int* __restrict__ deg,
                                                    int* __restrict__ rptr,
                                                    int* __restrict__ bsum, int n) {
    __shared__ int s[SCAN_B];
    int i = blockIdx.x * SCAN_B + threadIdx.x;
    int v = (i < n) ? deg[i] : 0;
    s[threadIdx.x] = v;
    __syncthreads();
    #pragma unroll
    for (int off = 1; off < SCAN_B; off <<= 1) {
        int t = (threadIdx.x >= off) ? s[threadIdx.x - off] : 0;
        __syncthreads();
        s[threadIdx.x] += t;
        __syncthreads();
    }
    if (i < n) rptr[i] = s[threadIdx.x] - v;
    if (threadIdx.x == SCAN_B - 1) bsum[blockIdx.x] = s[SCAN_B - 1];
}

__global__ __launch_bounds__(512) void scanB_kernel(int* __restrict__ bsum, int nb) {
    __shared__ int s[512];
    int t = threadIdx.x;
    int v = (t < nb) ? bsum[t] : 0;
    s[t] = v;
    __syncthreads();
    #pragma unroll
    for (int off = 1; off < 512; off <<= 1) {
        int x = (t >= off) ? s[t - off] : 0;
        __syncthreads();
        s[t] += x;
        __syncthreads();
    }
    if (t < nb) bsum[t] = s[t] - v;
}

__global__ __launch_bounds__(256) void scanC_kernel(int* __restrict__ rptr,
                                                    const int* __restrict__ bsum,
                                                    int n, int E) {
    int i = blockIdx.x * SCAN_B + threadIdx.x;
    if (i < n) rptr[i] += bsum[blockIdx.x];
    if (i == 0) rptr[n] = E;
}

// ---------------------------------------------------------------------------
// MERGED: blocks [0, G1_BLOCKS) = GEMM1 ; blocks [G1_BLOCKS, +FILL_BLOCKS) = fill
// fill writes PACKED cv: u32 = (col << 15) | (fp16(val) with sign bit dropped)
// ---------------------------------------------------------------------------
__global__ __launch_bounds__(256) void fill_gemm1_kernel(
        const float* __restrict__ A, const _Float16* __restrict__ BT,
        _Float16* __restrict__ C, int M,
        const int* __restrict__ erow, const int* __restrict__ ecol,
        const float* __restrict__ evals, const int* __restrict__ rptr,
        const unsigned short* __restrict__ ke, unsigned* __restrict__ cvp, int E) {
    __shared__ __align__(16) char smem[33792];

    if (blockIdx.x >= G1_BLOCKS) {
        // ---- fill: permute packed (col,val) -> CSR slots, no atomics ----
        int e = (blockIdx.x - G1_BLOCKS) * 256 + threadIdx.x;
        if (e < E) {
            int p = rptr[erow[e]] + ke[e];
            _Float16 h = (_Float16)evals[e];
            unsigned short hb = *(unsigned short*)&h;
            cvp[p] = ((unsigned)ecol[e] << 15) | (unsigned)(hb & 0x7FFFu);
        }
        return;
    }

    // ---- GEMM1 (MFMA fp16): tile 64(M) x 256(N), x read once ----
    _Float16 (*As)[40]  = (_Float16 (*)[40])smem;              //  64x40  = 5120 B
    _Float16 (*Bs)[40]  = (_Float16 (*)[40])(smem + 5120);     // 256x40  = 20480 B
    _Float16 (*sC)[264] = (_Float16 (*)[264])smem;             //  64x264 = 33792 B

    const int t    = threadIdx.x;
    const int m0   = blockIdx.x * 64;
    const int lane = t & 63;
    const int wid  = t >> 6;
    const int lr   = lane & 15, lk = lane >> 4;

    f32x4 acc[4][4] = {};

    const int  ar   = t >> 2;            // 0..63
    const int  aq   = t & 3;             // 0..3
    const bool aval = (m0 + ar) < M;
    const float*    aptr = A  + (size_t)(m0 + ar) * F_IN + aq * 8;
    const _Float16* bptr = BT + (size_t)t * F_IN;              // row t of BT

    float4 a0 = {0.f,0.f,0.f,0.f}, a1 = {0.f,0.f,0.f,0.f};
    half8 b0, b1, b2, b3;
    if (aval) { a0 = *(const float4*)(aptr); a1 = *(const float4*)(aptr + 4); }
    { const half8* bp = (const half8*)(bptr); b0 = bp[0]; b1 = bp[1]; b2 = bp[2]; b3 = bp[3]; }

    for (int k0 = 0; k0 < F_IN; k0 += 32) {
        half8 ah;
        ah[0]=(_Float16)a0.x; ah[1]=(_Float16)a0.y; ah[2]=(_Float16)a0.z; ah[3]=(_Float16)a0.w;
        ah[4]=(_Float16)a1.x; ah[5]=(_Float16)a1.y; ah[6]=(_Float16)a1.z; ah[7]=(_Float16)a1.w;
        *(half8*)&As[ar][aq * 8] = ah;
        *(half8*)&Bs[t][0]  = b0;
        *(half8*)&Bs[t][8]  = b1;
        *(half8*)&Bs[t][16] = b2;
        *(half8*)&Bs[t][24] = b3;
        __syncthreads();

        if (k0 + 32 < F_IN) {
            if (aval) {
                a0 = *(const float4*)(aptr + k0 + 32);
                a1 = *(const float4*)(aptr + k0 + 36);
            }
            const half8* bp = (const half8*)(bptr + k0 + 32);
            b0 = bp[0]; b1 = bp[1]; b2 = bp[2]; b3 = bp[3];
        }

        half8 af[4], bf[4];
        #pragma unroll
        for (int fm = 0; fm < 4; fm++) af[fm] = *(half8*)&As[fm * 16 + lr][lk * 8];
        #pragma unroll
        for (int fn = 0; fn < 4; fn++) bf[fn] = *(half8*)&Bs[wid * 64 + fn * 16 + lr][lk * 8];
        #pragma unroll
        for (int fm = 0; fm < 4; fm++)
            #pragma unroll
            for (int fn = 0; fn < 4; fn++)
                acc[fm][fn] = __builtin_amdgcn_mfma_f32_16x16x32_f16(af[fm], bf[fn], acc[fm][fn], 0, 0, 0);
        __syncthreads();
    }

    #pragma unroll
    for (int fm = 0; fm < 4; fm++)
        #pragma unroll
        for (int fn = 0; fn < 4; fn++)
            #pragma unroll
            for (int j = 0; j < 4; j++) {
                int row = fm * 16 + lk * 4 + j;
                int col = wid * 64 + fn * 16 + lr;
                sC[row][col] = (_Float16)acc[fm][fn][j];
            }
    __syncthreads();

    int m = m0 + ar;
    if (m < M) {
        const float4* sp = (const float4*)&sC[ar][aq * 64];
        float4*       dp = (float4*)(C + (size_t)m * HIDDEN + aq * 64);
        #pragma unroll
        for (int j = 0; j < 8; j++) dp[j] = sp[j];
    }
}

// ---------------------------------------------------------------------------
// FUSED: SpMM gather D=256 (fp16) + ReLU + GEMM2 (@W2 via MFMA epilogue).
// 1024 threads = 16 waves = 16 rows; rows staged in LDS; one barrier;
// wave 0 computes H2[16 rows][48] with 24 MFMAs. Tail slots clamp to e1-1
// (just-fetched line, L1-hot) with v=0.
// ---------------------------------------------------------------------------
__global__ __launch_bounds__(1024) void spmm_gemm2_kernel(const int* __restrict__ rptr,
                                                          const unsigned* __restrict__ cvp,
                                                          const _Float16* __restrict__ H1,
                                                          const _Float16* __restrict__ W2T,
                                                          _Float16* __restrict__ H2) {
    __shared__ _Float16 sW2[NPAD][264];     // 25344 B
    __shared__ _Float16 sRow[16][264];      //  8448 B

    int t = threadIdx.x;
    int wave = t >> 6, lane = t & 63;
    int m0 = blockIdx.x * FB_ROWS;
    int r = m0 + wave;

    // stage W2T (48x256 = 1536 half8 chunks) : 1.5 per thread
    #pragma unroll
    for (int i = 0; i < 2; i++) {
        int idx = t + i * 1024;             // 0..2047
        if (idx < NPAD * 32) {
            int row = idx >> 5, c8 = idx & 31;
            *(half8*)&sW2[row][c8 * 8] = *(const half8*)(W2T + (size_t)row * HIDDEN + c8 * 8);
        }
    }

    // gather: 2 edges per instr (32 lanes x 16B cover one 512B row), 8 edges/iter
    int e0 = rptr[r], e1 = rptr[r + 1];
    int hf = lane >> 5;
    int fl = lane & 31;

    float acc[8] = {};
    for (int e = e0; e < e1; e += 8) {
        #pragma unroll
        for (int u = 0; u < 4; u++) {
            int idx = e + 2 * u + hf;
            bool ok = idx < e1;
            unsigned pk = cvp[ok ? idx : (e1 - 1)];
            float v = ok ? unpack_val(pk) : 0.f;
            int col = (int)(pk >> 15);
            half8 h = *(const half8*)(H1 + (size_t)col * HIDDEN + fl * 8);
            #pragma unroll
            for (int j = 0; j < 8; j++)
                acc[j] += v * (float)h[j];
        }
    }
    #pragma unroll
    for (int j = 0; j < 8; j++)
        acc[j] += __shfl_xor(acc[j], 32);

    if (hf == 0) {
        half8 o;
        #pragma unroll
        for (int j = 0; j < 8; j++) o[j] = (_Float16)fmaxf(acc[j], 0.f);
        *(half8*)&sRow[wave][fl * 8] = o;
    }
    __syncthreads();

    // MFMA epilogue on wave 0: [16x256] @ [48x256]^T
    if (wave == 0) {
        int lr = lane & 15, lk = lane >> 4;
        f32x4 acc2[3] = {};
        #pragma unroll
        for (int ks = 0; ks < 8; ks++) {
            half8 af = *(half8*)&sRow[lr][ks * 32 + lk * 8];
            #pragma unroll
            for (int fn = 0; fn < 3; fn++) {
                half8 bf = *(half8*)&sW2[fn * 16 + lr][ks * 32 + lk * 8];
                acc2[fn] = __builtin_amdgcn_mfma_f32_16x16x32_f16(af, bf, acc2[fn], 0, 0, 0);
            }
        }
        #pragma unroll
        for (int fn = 0; fn < 3; fn++)
            #pragma unroll
            for (int j = 0; j < 4; j++) {
                int row = lk * 4 + j;       // 0..15
                int col = fn * 16 + lr;     // 0..47
                H2[(size_t)(m0 + row) * H2STRIDE + col] = (_Float16)acc2[fn][j];
            }
    }
}

// ---------------------------------------------------------------------------
// SpMM gather D=40 (fp16, stride-64 rows = one 128B line/edge) + ReLU +
// log_softmax. One wave per row; 24 edges/iter; tail clamps to e1-1.
// ---------------------------------------------------------------------------
__global__ __launch_bounds__(256) void spmm40_ls_kernel(const int* __restrict__ rptr,
                                                        const unsigned* __restrict__ cvp,
                                                        const _Float16* __restrict__ H2,
                                                        float* __restrict__ out) {
    int t = threadIdx.x;
    int wave = t >> 6, lane = t & 63;
    int r = blockIdx.x * 4 + wave;

    int e0 = rptr[r], e1 = rptr[r + 1];
    int s = lane / 5;           // edge slot 0..11 (lane 60..63 inactive)
    int g = lane % 5;           // feature block: classes g*8 .. g*8+7
    bool lact = lane < 60;

    float acc[8] = {};
    for (int e = e0; e < e1; e += 24) {
        int idx0 = e + s, idx1 = e + 12 + s;
        bool ok0 = lact && (idx0 < e1);
        bool ok1 = lact && (idx1 < e1);
        unsigned pk0 = cvp[ok0 ? idx0 : (e1 - 1)];
        unsigned pk1 = cvp[ok1 ? idx1 : (e1 - 1)];
        float v0 = ok0 ? unpack_val(pk0) : 0.f;
        float v1 = ok1 ? unpack_val(pk1) : 0.f;
        int c0 = (int)(pk0 >> 15), c1 = (int)(pk1 >> 15);
        half8 h0 = *(const half8*)(H2 + (size_t)c0 * H2STRIDE + g * 8);
        half8 h1 = *(const half8*)(H2 + (size_t)c1 * H2STRIDE + g * 8);
        #pragma unroll
        for (int j = 0; j < 8; j++)
            acc[j] += v0 * (float)h0[j] + v1 * (float)h1[j];
    }

    // slot-tree reduce: 12 -> 6 -> 3 -> 1
    #pragma unroll
    for (int j = 0; j < 8; j++) acc[j] += __shfl(acc[j], lane + 30);
    #pragma unroll
    for (int j = 0; j < 8; j++) acc[j] += __shfl(acc[j], lane + 15);
    #pragma unroll
    for (int j = 0; j < 8; j++) {
        float t1 = __shfl(acc[j], lane + 5);
        float t2 = __shfl(acc[j], lane + 10);
        acc[j] += t1 + t2;
    }

    bool act = lane < 5;
    float z[8];
    float mx = -INFINITY;
    #pragma unroll
    for (int j = 0; j < 8; j++) {
        z[j] = act ? fmaxf(acc[j], 0.f) : -INFINITY;
        mx = fmaxf(mx, z[j]);
    }
    mx = fmaxf(mx, __shfl_xor(mx, 1));
    mx = fmaxf(mx, __shfl_xor(mx, 2));
    mx = fmaxf(mx, __shfl_xor(mx, 4));

    float sm = 0.f;
    #pragma unroll
    for (int j = 0; j < 8; j++)
        sm += act ? expf(z[j] - mx) : 0.f;
    sm += __shfl_xor(sm, 1);
    sm += __shfl_xor(sm, 2);
    sm += __shfl_xor(sm, 4);

    float lse = logf(sm);
    if (act) {
        float4 o0 = {z[0]-mx-lse, z[1]-mx-lse, z[2]-mx-lse, z[3]-mx-lse};
        float4 o1 = {z[4]-mx-lse, z[5]-mx-lse, z[6]-mx-lse, z[7]-mx-lse};
        float4* dp = (float4*)(out + (size_t)r * NCLASS + g * 8);
        dp[0] = o0;
        dp[1] = o1;
    }
}

// ---------------------------------------------------------------------------
extern "C" void kernel_launch(void* const* d_in, const int* in_sizes, int n_in,
                              void* d_out, int out_size, void* d_ws, size_t ws_size,
                              hipStream_t stream) {
    const float* x     = (const float*)d_in[0];
    const int*   erow  = (const int*)d_in[1];
    const int*   ecol  = (const int*)d_in[2];
    const float* evals = (const float*)d_in[3];
    const float* W1    = (const float*)d_in[4];
    const float* W2    = (const float*)d_in[5];
    float* out = (float*)d_out;

    const int M = N_NODES;
    const int E = N_EDGES;

    char* p = (char*)d_ws;
    auto alloc = [&](size_t bytes) {
        char* q = p;
        p += (bytes + 255) & ~(size_t)255;
        return q;
    };
    int*            deg  = (int*)alloc(sizeof(int) * N_NODES);
    int*            rptr = (int*)alloc(sizeof(int) * (N_NODES + 1));
    int*            bsum = (int*)alloc(sizeof(int) * 512);
    unsigned short* ke   = (unsigned short*)alloc(sizeof(unsigned short) * N_EDGES); // 6.4 MB
    unsigned*       cvp  = (unsigned*)alloc(sizeof(unsigned) * N_EDGES);             // 12.8 MB
    _Float16*       W1T  = (_Float16*)alloc(sizeof(_Float16) * F_IN * HIDDEN);
    _Float16*       W2T  = (_Float16*)alloc(sizeof(_Float16) * NPAD * HIDDEN);
    _Float16*       H1   = (_Float16*)alloc(sizeof(_Float16) * (size_t)N_NODES * HIDDEN);   // 51.2 MB
    _Float16*       H2   = (_Float16*)alloc(sizeof(_Float16) * (size_t)N_NODES * H2STRIDE); // 12.8 MB

    // K1: deg=0 + weight conversions
    init_kernel<<<(F_IN * HIDDEN) / 256, 256, 0, stream>>>(W1, W2, W1T, W2T, deg);

    // K2: histogram + per-edge rank
    hist2_kernel<<<E / 256, 256, 0, stream>>>(erow, deg, ke, E);

    // K3-K5: exclusive scan of deg -> rptr
    scanA_kernel<<<N_SCANB, SCAN_B, 0, stream>>>(deg, rptr, bsum, N_NODES);
    scanB_kernel<<<1, 512, 0, stream>>>(bsum, N_SCANB);
    scanC_kernel<<<N_SCANB, SCAN_B, 0, stream>>>(rptr, bsum, N_NODES, E);

    // K6: merged GEMM1 (blocks 0..1562)  ||  CSR fill (blocks 1563..14062)
    fill_gemm1_kernel<<<G1_BLOCKS + FILL_BLOCKS, 256, 0, stream>>>(
        x, W1T, H1, M, erow, ecol, evals, rptr, ke, cvp, E);

    // K7: fused layer-1 aggregation + relu + @W2 (MFMA epilogue), 16 rows/block
    spmm_gemm2_kernel<<<M / FB_ROWS, 1024, 0, stream>>>(rptr, cvp, H1, W2T, H2);

    // K8: layer-2 aggregation + relu + log_softmax
    spmm40_ls_kernel<<<M / 4, 256, 0, stream>>>(rptr, cvp, H2, out);
}

// Round 11
// 518.215 us; speedup vs baseline: 1.1728x; 1.1312x over previous
//
#include <hip/hip_runtime.h>
#include <math.h>

#define N_NODES 100000
#define N_EDGES 3200000
#define F_IN    512
#define HIDDEN  256
#define NCLASS  40
#define NPAD    48
#define H2STRIDE 64
#define FB_ROWS 16
#define G1_BLOCKS ((N_NODES + 63) / 64)          // 1563
#define FILL_BLOCKS (N_EDGES / 256)              // 12500

#define SCAN_B  256
#define N_SCANB ((N_NODES + SCAN_B - 1) / SCAN_B)   // 391

typedef __attribute__((ext_vector_type(8))) _Float16 half8;
typedef __attribute__((ext_vector_type(4))) _Float16 half4;
typedef __attribute__((ext_vector_type(4))) float    f32x4;
typedef __attribute__((ext_vector_type(2))) float    f32x2;

__device__ __forceinline__ float unpack_val(unsigned pk) {
    unsigned short hb = (unsigned short)(pk & 0x7FFFu);
    _Float16 h = *(_Float16*)&hb;
    return (float)h;
}

// ---------------------------------------------------------------------------
// init: deg = 0  +  W1 -> W1T [256][512] fp16  +  W2 -> W2T [48][256] fp16
// ---------------------------------------------------------------------------
__global__ __launch_bounds__(256) void init_kernel(const float* __restrict__ W1,
                                                   const float* __restrict__ W2,
                                                   _Float16* __restrict__ W1T,
                                                   _Float16* __restrict__ W2T,
                                                   int* __restrict__ deg) {
    int o = blockIdx.x * 256 + threadIdx.x;   // 0..131071
    {
        int n = o >> 9, k = o & 511;
        W1T[o] = (_Float16)W1[(size_t)k * HIDDEN + n];
    }
    if (o < NPAD * HIDDEN) {                  // 0..12287
        int n = o >> 8, k = o & 255;
        W2T[o] = (n < NCLASS) ? (_Float16)W2[(size_t)k * NCLASS + n] : (_Float16)0.f;
    }
    if (o < N_NODES) deg[o] = 0;
}

// ---------------------------------------------------------------------------
// CSR build: pass 1 = histogram + per-edge rank (atomic return value)
// ---------------------------------------------------------------------------
__global__ __launch_bounds__(256) void hist2_kernel(const int* __restrict__ erow,
                                                    int* __restrict__ deg,
                                                    unsigned short* __restrict__ ke, int E) {
    int e = blockIdx.x * 256 + threadIdx.x;
    if (e < E) ke[e] = (unsigned short)atomicAdd(&deg[erow[e]], 1);
}

__global__ __launch_bounds__(256) void scanA_kernel(const int* __restrict__ deg,
                                                    int* __restrict__ rptr,
                                                    int* __restrict__ bsum, int n) {
    __shared__ int s[SCAN_B];
    int i = blockIdx.x * SCAN_B + threadIdx.x;
    int v = (i < n) ? deg[i] : 0;
    s[threadIdx.x] = v;
    __syncthreads();
    #pragma unroll
    for (int off = 1; off < SCAN_B; off <<= 1) {
        int t = (threadIdx.x >= off) ? s[threadIdx.x - off] : 0;
        __syncthreads();
        s[threadIdx.x] += t;
        __syncthreads();
    }
    if (i < n) rptr[i] = s[threadIdx.x] - v;
    if (threadIdx.x == SCAN_B - 1) bsum[blockIdx.x] = s[SCAN_B - 1];
}

__global__ __launch_bounds__(512) void scanB_kernel(int* __restrict__ bsum, int nb) {
    __shared__ int s[512];
    int t = threadIdx.x;
    int v = (t < nb) ? bsum[t] : 0;
    s[t] = v;
    __syncthreads();
    #pragma unroll
    for (int off = 1; off < 512; off <<= 1) {
        int x = (t >= off) ? s[t - off] : 0;
        __syncthreads();
        s[t] += x;
        __syncthreads();
    }
    if (t < nb) bsum[t] = s[t] - v;
}

__global__ __launch_bounds__(256) void scanC_kernel(int* __restrict__ rptr,
                                                    const int* __restrict__ bsum,
                                                    int n, int E) {
    int i = blockIdx.x * SCAN_B + threadIdx.x;
    if (i < n) rptr[i] += bsum[blockIdx.x];
    if (i == 0) rptr[n] = E;
}

// ---------------------------------------------------------------------------
// MERGED: blocks [0, G1_BLOCKS) = GEMM1 ; blocks [G1_BLOCKS, +FILL_BLOCKS) = fill
// fill writes PACKED cv: u32 = (col << 15) | (fp16(val) with sign bit dropped)
// GEMM1 output H1 is fp8 e4m3 (256 B/row).
// ---------------------------------------------------------------------------
__global__ __launch_bounds__(256) void fill_gemm1_kernel(
        const float* __restrict__ A, const _Float16* __restrict__ BT,
        unsigned char* __restrict__ C, int M,
        const int* __restrict__ erow, const int* __restrict__ ecol,
        const float* __restrict__ evals, const int* __restrict__ rptr,
        const unsigned short* __restrict__ ke, unsigned* __restrict__ cvp, int E) {
    __shared__ __align__(16) char smem[33792];

    if (blockIdx.x >= G1_BLOCKS) {
        // ---- fill: permute packed (col,val) -> CSR slots, no atomics ----
        int e = (blockIdx.x - G1_BLOCKS) * 256 + threadIdx.x;
        if (e < E) {
            int p = rptr[erow[e]] + ke[e];
            _Float16 h = (_Float16)evals[e];
            unsigned short hb = *(unsigned short*)&h;
            cvp[p] = ((unsigned)ecol[e] << 15) | (unsigned)(hb & 0x7FFFu);
        }
        return;
    }

    // ---- GEMM1 (MFMA fp16): tile 64(M) x 256(N), x read once ----
    _Float16 (*As)[40]  = (_Float16 (*)[40])smem;              //  64x40  = 5120 B
    _Float16 (*Bs)[40]  = (_Float16 (*)[40])(smem + 5120);     // 256x40  = 20480 B
    _Float16 (*sC)[264] = (_Float16 (*)[264])smem;             //  64x264 = 33792 B

    const int t    = threadIdx.x;
    const int m0   = blockIdx.x * 64;
    const int lane = t & 63;
    const int wid  = t >> 6;
    const int lr   = lane & 15, lk = lane >> 4;

    f32x4 acc[4][4] = {};

    const int  ar   = t >> 2;            // 0..63
    const int  aq   = t & 3;             // 0..3
    const bool aval = (m0 + ar) < M;
    const float*    aptr = A  + (size_t)(m0 + ar) * F_IN + aq * 8;
    const _Float16* bptr = BT + (size_t)t * F_IN;              // row t of BT

    float4 a0 = {0.f,0.f,0.f,0.f}, a1 = {0.f,0.f,0.f,0.f};
    half8 b0, b1, b2, b3;
    if (aval) { a0 = *(const float4*)(aptr); a1 = *(const float4*)(aptr + 4); }
    { const half8* bp = (const half8*)(bptr); b0 = bp[0]; b1 = bp[1]; b2 = bp[2]; b3 = bp[3]; }

    for (int k0 = 0; k0 < F_IN; k0 += 32) {
        half8 ah;
        ah[0]=(_Float16)a0.x; ah[1]=(_Float16)a0.y; ah[2]=(_Float16)a0.z; ah[3]=(_Float16)a0.w;
        ah[4]=(_Float16)a1.x; ah[5]=(_Float16)a1.y; ah[6]=(_Float16)a1.z; ah[7]=(_Float16)a1.w;
        *(half8*)&As[ar][aq * 8] = ah;
        *(half8*)&Bs[t][0]  = b0;
        *(half8*)&Bs[t][8]  = b1;
        *(half8*)&Bs[t][16] = b2;
        *(half8*)&Bs[t][24] = b3;
        __syncthreads();

        if (k0 + 32 < F_IN) {
            if (aval) {
                a0 = *(const float4*)(aptr + k0 + 32);
                a1 = *(const float4*)(aptr + k0 + 36);
            }
            const half8* bp = (const half8*)(bptr + k0 + 32);
            b0 = bp[0]; b1 = bp[1]; b2 = bp[2]; b3 = bp[3];
        }

        half8 af[4], bf[4];
        #pragma unroll
        for (int fm = 0; fm < 4; fm++) af[fm] = *(half8*)&As[fm * 16 + lr][lk * 8];
        #pragma unroll
        for (int fn = 0; fn < 4; fn++) bf[fn] = *(half8*)&Bs[wid * 64 + fn * 16 + lr][lk * 8];
        #pragma unroll
        for (int fm = 0; fm < 4; fm++)
            #pragma unroll
            for (int fn = 0; fn < 4; fn++)
                acc[fm][fn] = __builtin_amdgcn_mfma_f32_16x16x32_f16(af[fm], bf[fn], acc[fm][fn], 0, 0, 0);
        __syncthreads();
    }

    #pragma unroll
    for (int fm = 0; fm < 4; fm++)
        #pragma unroll
        for (int fn = 0; fn < 4; fn++)
            #pragma unroll
            for (int j = 0; j < 4; j++) {
                int row = fm * 16 + lk * 4 + j;
                int col = wid * 64 + fn * 16 + lr;
                sC[row][col] = (_Float16)acc[fm][fn][j];
            }
    __syncthreads();

    int m = m0 + ar;
    if (m < M) {
        // read 64 fp16 from LDS, convert to 64 fp8 e4m3, write 64 B
        const half8* sp = (const half8*)&sC[ar][aq * 64];
        unsigned w[16];
        #pragma unroll
        for (int c = 0; c < 8; c++) {
            half8 hv = sp[c];
            unsigned lo = __builtin_amdgcn_cvt_pk_fp8_f32((float)hv[0], (float)hv[1], 0u, false);
            lo = __builtin_amdgcn_cvt_pk_fp8_f32((float)hv[2], (float)hv[3], lo, true);
            unsigned hi = __builtin_amdgcn_cvt_pk_fp8_f32((float)hv[4], (float)hv[5], 0u, false);
            hi = __builtin_amdgcn_cvt_pk_fp8_f32((float)hv[6], (float)hv[7], hi, true);
            w[c * 2]     = lo;
            w[c * 2 + 1] = hi;
        }
        uint4* dp = (uint4*)(C + (size_t)m * HIDDEN + aq * 64);
        #pragma unroll
        for (int c = 0; c < 4; c++)
            dp[c] = make_uint4(w[c*4], w[c*4+1], w[c*4+2], w[c*4+3]);
    }
}

// ---------------------------------------------------------------------------
// FUSED: SpMM gather D=256 (fp8 table) + ReLU + GEMM2 (@W2 via MFMA epilogue).
// 1024 threads = 16 waves = 16 rows. 4 edges per gather instruction
// (16 lanes x 16B cover one 256B fp8 row); 16 edges (4 loads) in flight.
// Quad merge via shfl_xor(32,16); lanes 0..15 stage the relu'd fp16 row.
// ---------------------------------------------------------------------------
__global__ __launch_bounds__(1024) void spmm_gemm2_kernel(const int* __restrict__ rptr,
                                                          const unsigned* __restrict__ cvp,
                                                          const unsigned char* __restrict__ H1,
                                                          const _Float16* __restrict__ W2T,
                                                          _Float16* __restrict__ H2) {
    __shared__ _Float16 sW2[NPAD][264];     // 25344 B
    __shared__ _Float16 sRow[16][264];      //  8448 B

    int t = threadIdx.x;
    int wave = t >> 6, lane = t & 63;
    int m0 = blockIdx.x * FB_ROWS;
    int r = m0 + wave;

    // stage W2T (48x256 = 1536 half8 chunks) : 1.5 per thread
    #pragma unroll
    for (int i = 0; i < 2; i++) {
        int idx = t + i * 1024;             // 0..2047
        if (idx < NPAD * 32) {
            int row = idx >> 5, c8 = idx & 31;
            *(half8*)&sW2[row][c8 * 8] = *(const half8*)(W2T + (size_t)row * HIDDEN + c8 * 8);
        }
    }

    int e0 = rptr[r], e1 = rptr[r + 1];
    int qf = lane >> 4;            // which edge of the quad (0..3)
    int fl = lane & 15;            // 16B feature block (16 fp8 each)

    float acc[16] = {};
    for (int e = e0; e < e1; e += 16) {
        #pragma unroll
        for (int u = 0; u < 4; u++) {
            int idx = e + 4 * u + qf;
            bool ok = idx < e1;
            unsigned pk = cvp[ok ? idx : (e1 - 1)];
            float v = ok ? unpack_val(pk) : 0.f;
            int col = (int)(pk >> 15);
            uint4 raw = *(const uint4*)(H1 + (size_t)col * HIDDEN + fl * 16);
            #pragma unroll
            for (int q = 0; q < 4; q++) {
                unsigned wq = (q == 0) ? raw.x : (q == 1) ? raw.y : (q == 2) ? raw.z : raw.w;
                f32x2 lo = __builtin_amdgcn_cvt_pk_f32_fp8(wq, false);
                f32x2 hi = __builtin_amdgcn_cvt_pk_f32_fp8(wq, true);
                acc[q*4 + 0] += v * lo[0];
                acc[q*4 + 1] += v * lo[1];
                acc[q*4 + 2] += v * hi[0];
                acc[q*4 + 3] += v * hi[1];
            }
        }
    }
    // merge the 4 quad groups: lanes 0..15 end with the full sums
    #pragma unroll
    for (int j = 0; j < 16; j++) {
        acc[j] += __shfl_xor(acc[j], 32);
        acc[j] += __shfl_xor(acc[j], 16);
    }

    if (lane < 16) {
        half8 o0, o1;
        #pragma unroll
        for (int j = 0; j < 8; j++) {
            o0[j] = (_Float16)fmaxf(acc[j], 0.f);
            o1[j] = (_Float16)fmaxf(acc[8 + j], 0.f);
        }
        *(half8*)&sRow[wave][fl * 16]     = o0;
        *(half8*)&sRow[wave][fl * 16 + 8] = o1;
    }
    __syncthreads();

    // MFMA epilogue on wave 0: [16x256] @ [48x256]^T
    if (wave == 0) {
        int lr = lane & 15, lk = lane >> 4;
        f32x4 acc2[3] = {};
        #pragma unroll
        for (int ks = 0; ks < 8; ks++) {
            half8 af = *(half8*)&sRow[lr][ks * 32 + lk * 8];
            #pragma unroll
            for (int fn = 0; fn < 3; fn++) {
                half8 bf = *(half8*)&sW2[fn * 16 + lr][ks * 32 + lk * 8];
                acc2[fn] = __builtin_amdgcn_mfma_f32_16x16x32_f16(af, bf, acc2[fn], 0, 0, 0);
            }
        }
        #pragma unroll
        for (int fn = 0; fn < 3; fn++)
            #pragma unroll
            for (int j = 0; j < 4; j++) {
                int row = lk * 4 + j;       // 0..15
                int col = fn * 16 + lr;     // 0..47
                H2[(size_t)(m0 + row) * H2STRIDE + col] = (_Float16)acc2[fn][j];
            }
    }
}

// ---------------------------------------------------------------------------
// SpMM gather D=40 (fp16, stride-64 rows = one 128B line/edge) + ReLU +
// log_softmax. One wave per row; 24 edges/iter; tail clamps to e1-1.
// ---------------------------------------------------------------------------
__global__ __launch_bounds__(256) void spmm40_ls_kernel(const int* __restrict__ rptr,
                                                        const unsigned* __restrict__ cvp,
                                                        const _Float16* __restrict__ H2,
                                                        float* __restrict__ out) {
    int t = threadIdx.x;
    int wave = t >> 6, lane = t & 63;
    int r = blockIdx.x * 4 + wave;

    int e0 = rptr[r], e1 = rptr[r + 1];
    int s = lane / 5;           // edge slot 0..11 (lane 60..63 inactive)
    int g = lane % 5;           // feature block: classes g*8 .. g*8+7
    bool lact = lane < 60;

    float acc[8] = {};
    for (int e = e0; e < e1; e += 24) {
        int idx0 = e + s, idx1 = e + 12 + s;
        bool ok0 = lact && (idx0 < e1);
        bool ok1 = lact && (idx1 < e1);
        unsigned pk0 = cvp[ok0 ? idx0 : (e1 - 1)];
        unsigned pk1 = cvp[ok1 ? idx1 : (e1 - 1)];
        float v0 = ok0 ? unpack_val(pk0) : 0.f;
        float v1 = ok1 ? unpack_val(pk1) : 0.f;
        int c0 = (int)(pk0 >> 15), c1 = (int)(pk1 >> 15);
        half8 h0 = *(const half8*)(H2 + (size_t)c0 * H2STRIDE + g * 8);
        half8 h1 = *(const half8*)(H2 + (size_t)c1 * H2STRIDE + g * 8);
        #pragma unroll
        for (int j = 0; j < 8; j++)
            acc[j] += v0 * (float)h0[j] + v1 * (float)h1[j];
    }

    // slot-tree reduce: 12 -> 6 -> 3 -> 1
    #pragma unroll
    for (int j = 0; j < 8; j++) acc[j] += __shfl(acc[j], lane + 30);
    #pragma unroll
    for (int j = 0; j < 8; j++) acc[j] += __shfl(acc[j], lane + 15);
    #pragma unroll
    for (int j = 0; j < 8; j++) {
        float t1 = __shfl(acc[j], lane + 5);
        float t2 = __shfl(acc[j], lane + 10);
        acc[j] += t1 + t2;
    }

    bool act = lane < 5;
    float z[8];
    float mx = -INFINITY;
    #pragma unroll
    for (int j = 0; j < 8; j++) {
        z[j] = act ? fmaxf(acc[j], 0.f) : -INFINITY;
        mx = fmaxf(mx, z[j]);
    }
    mx = fmaxf(mx, __shfl_xor(mx, 1));
    mx = fmaxf(mx, __shfl_xor(mx, 2));
    mx = fmaxf(mx, __shfl_xor(mx, 4));

    float sm = 0.f;
    #pragma unroll
    for (int j = 0; j < 8; j++)
        sm += act ? expf(z[j] - mx) : 0.f;
    sm += __shfl_xor(sm, 1);
    sm += __shfl_xor(sm, 2);
    sm += __shfl_xor(sm, 4);

    float lse = logf(sm);
    if (act) {
        float4 o0 = {z[0]-mx-lse, z[1]-mx-lse, z[2]-mx-lse, z[3]-mx-lse};
        float4 o1 = {z[4]-mx-lse, z[5]-mx-lse, z[6]-mx-lse, z[7]-mx-lse};
        float4* dp = (float4*)(out + (size_t)r * NCLASS + g * 8);
        dp[0] = o0;
        dp[1] = o1;
    }
}

// ---------------------------------------------------------------------------
extern "C" void kernel_launch(void* const* d_in, const int* in_sizes, int n_in,
                              void* d_out, int out_size, void* d_ws, size_t ws_size,
                              hipStream_t stream) {
    const float* x     = (const float*)d_in[0];
    const int*   erow  = (const int*)d_in[1];
    const int*   ecol  = (const int*)d_in[2];
    const float* evals = (const float*)d_in[3];
    const float* W1    = (const float*)d_in[4];
    const float* W2    = (const float*)d_in[5];
    float* out = (float*)d_out;

    const int M = N_NODES;
    const int E = N_EDGES;

    char* p = (char*)d_ws;
    auto alloc = [&](size_t bytes) {
        char* q = p;
        p += (bytes + 255) & ~(size_t)255;
        return q;
    };
    int*            deg  = (int*)alloc(sizeof(int) * N_NODES);
    int*            rptr = (int*)alloc(sizeof(int) * (N_NODES + 1));
    int*            bsum = (int*)alloc(sizeof(int) * 512);
    unsigned short* ke   = (unsigned short*)alloc(sizeof(unsigned short) * N_EDGES); // 6.4 MB
    unsigned*       cvp  = (unsigned*)alloc(sizeof(unsigned) * N_EDGES);             // 12.8 MB
    _Float16*       W1T  = (_Float16*)alloc(sizeof(_Float16) * F_IN * HIDDEN);
    _Float16*       W2T  = (_Float16*)alloc(sizeof(_Float16) * NPAD * HIDDEN);
    unsigned char*  H1   = (unsigned char*)alloc((size_t)N_NODES * HIDDEN);          // 25.6 MB fp8
    _Float16*       H2   = (_Float16*)alloc(sizeof(_Float16) * (size_t)N_NODES * H2STRIDE); // 12.8 MB

    // K1: deg=0 + weight conversions
    init_kernel<<<(F_IN * HIDDEN) / 256, 256, 0, stream>>>(W1, W2, W1T, W2T, deg);

    // K2: histogram + per-edge rank
    hist2_kernel<<<E / 256, 256, 0, stream>>>(erow, deg, ke, E);

    // K3-K5: exclusive scan of deg -> rptr
    scanA_kernel<<<N_SCANB, SCAN_B, 0, stream>>>(deg, rptr, bsum, N_NODES);
    scanB_kernel<<<1, 512, 0, stream>>>(bsum, N_SCANB);
    scanC_kernel<<<N_SCANB, SCAN_B, 0, stream>>>(rptr, bsum, N_NODES, E);

    // K6: merged GEMM1-fp8-out (blocks 0..1562)  ||  CSR fill (blocks 1563..14062)
    fill_gemm1_kernel<<<G1_BLOCKS + FILL_BLOCKS, 256, 0, stream>>>(
        x, W1T, H1, M, erow, ecol, evals, rptr, ke, cvp, E);

    // K7: fused layer-1 aggregation (fp8 gather) + relu + @W2 (MFMA epilogue)
    spmm_gemm2_kernel<<<M / FB_ROWS, 1024, 0, stream>>>(rptr, cvp, H1, W2T, H2);

    // K8: layer-2 aggregation + relu + log_softmax
    spmm40_ls_kernel<<<M / 4, 256, 0, stream>>>(rptr, cvp, H2, out);
}